// Round 1
// baseline (569.111 us; speedup 1.0000x reference)
//
#include <hip/hip_runtime.h>
#include <stdint.h>

// Problem constants (fixed by setup_inputs)
#define B_ 64
#define C_ 256
#define H_ 56
#define W_ 56
#define HM 50              // H - (BLOCK_SIZE-1)
#define WM 50
#define NPLANES (B_ * C_)          // 16384
#define PLANE_IN (HM * WM)         // 2500
#define PLANE_OUT (H_ * W_)        // 3136
#define NTOT (NPLANES * PLANE_OUT) // 51,380,224
#define N4 (NTOT / 4)              // 12,845,056 float4s

typedef float f4 __attribute__((ext_vector_type(4)));

// One block per (b,c) plane, 4 waves. Each wave builds row bitmasks via
// __ballot (lane i supplies bit i), smears horizontally (7-wide OR), then
// 56 threads do the vertical 7-row OR, invert to keep-bits, store.
// Reduce kernel is folded in: one atomicAdd per block to a global counter
// (16384 adds total — contention-free enough, saves a serial dispatch).
__global__ __launch_bounds__(256) void dilate_kernel(
        const float* __restrict__ u,
        const float* __restrict__ gamma,
        unsigned long long* __restrict__ mask_out,   // [NPLANES * H_]
        unsigned int* __restrict__ total) {          // single counter, pre-zeroed
    __shared__ unsigned long long hdil[HM];    // 400 B

    const int plane = blockIdx.x;
    const int tid   = threadIdx.x;
    const int wave  = tid >> 6;
    const int lane  = tid & 63;
    const float g   = gamma[0];
    const float* up = u + (size_t)plane * PLANE_IN;

    // Rows r = wave + 4*i. Lanes 0..49 load row floats (contiguous 200 B),
    // ballot packs the predicate into a 64-bit row mask in one instruction.
    #pragma unroll
    for (int i = 0; i < 13; ++i) {
        int r = wave + 4 * i;
        float v = 1e30f;                       // predicate false for idle lanes
        if (r < HM && lane < WM) v = up[r * WM + lane];
        unsigned long long bits = __ballot(v < g);
        // horizontal dilation: OR of shifts 0..6 via log-step smear
        unsigned long long h = bits | (bits << 1);
        h |= h << 2;
        h |= h << 3;
        if (lane == 0 && r < HM) hdil[r] = h;
    }
    __syncthreads();

    // Vertical dilation: output row t covers seed rows [t-6, t] ∩ [0, HM).
    unsigned int zcnt = 0;
    if (tid < H_) {
        int r0 = tid - 6; if (r0 < 0) r0 = 0;
        int r1 = tid;     if (r1 > HM - 1) r1 = HM - 1;
        unsigned long long v = 0ull;
        for (int r = r0; r <= r1; ++r) v |= hdil[r];
        unsigned long long keep = (~v) & ((1ULL << W_) - 1ULL);
        mask_out[(size_t)plane * H_ + tid] = keep;
        zcnt = (unsigned int)__popcll(keep);
    }
    // Threads 0..55 are all in wave 0: shuffle-reduce, one atomic per block.
    if (tid < 64) {
        #pragma unroll
        for (int off = 32; off > 0; off >>= 1)
            zcnt += __shfl_down(zcnt, off, 64);
        if (tid == 0) atomicAdd(total, zcnt);
    }
}

// Grid-stride elementwise: out = x * scale * keep_bit.
// KEY: ~63% of pixels are dropped (gamma=0.02, 7x7 dilation -> keep = .98^49).
// Dropped runs are >=7 wide, so many full 64B cachelines of x are never
// needed — predicate the x load on (bits != 0) so masked-off lanes issue no
// memory request, cutting x FETCH roughly in half. Scale is computed inline
// from the integer total (bit-identical to the old reduce kernel's result).
// Nontemporal hints: x and out are streamed exactly once; keep the 7.3 MB
// mask resident in L2 instead.
__global__ __launch_bounds__(256) void apply_kernel(
        const float* __restrict__ x,
        const unsigned long long* __restrict__ mask,
        const unsigned int* __restrict__ total_ptr,
        float* __restrict__ out) {
    const float scale = (float)NTOT / (float)(*total_ptr);
    const f4* xp = (const f4*)x;
    f4*       op = (f4*)out;
    const int stride = gridDim.x * 256;

    for (int idx4 = blockIdx.x * 256 + threadIdx.x; idx4 < N4; idx4 += stride) {
        int word = idx4 / 14;            // = plane*56 + h  (W_/4 == 14)
        int w4   = idx4 - word * 14;
        unsigned int bits = (unsigned int)(mask[word] >> (w4 * 4)) & 0xFu;
        f4 o = {0.0f, 0.0f, 0.0f, 0.0f};
        if (bits) {                      // skip x fetch for fully-dropped quads
            f4 v = __builtin_nontemporal_load(&xp[idx4]);
            o.x = (bits & 1u) ? v.x * scale : 0.0f;
            o.y = (bits & 2u) ? v.y * scale : 0.0f;
            o.z = (bits & 4u) ? v.z * scale : 0.0f;
            o.w = (bits & 8u) ? v.w * scale : 0.0f;
        }
        __builtin_nontemporal_store(o, &op[idx4]);
    }
}

extern "C" void kernel_launch(void* const* d_in, const int* in_sizes, int n_in,
                              void* d_out, int out_size, void* d_ws, size_t ws_size,
                              hipStream_t stream) {
    const float* x     = (const float*)d_in[0];
    const float* u     = (const float*)d_in[1];
    const float* gamma = (const float*)d_in[2];
    float* out = (float*)d_out;

    // Workspace: [0,4) total-count; [1024, 1024+7.34MB) bit-packed keep mask.
    unsigned int* total = (unsigned int*)d_ws;
    unsigned long long* mask =
        (unsigned long long*)((char*)d_ws + 1024);

    hipMemsetAsync(total, 0, sizeof(unsigned int), stream);  // capturable node
    dilate_kernel<<<NPLANES, 256, 0, stream>>>(u, gamma, mask, total);
    apply_kernel<<<4096, 256, 0, stream>>>(x, mask, total, out);
}

// Round 2
// 459.240 us; speedup vs baseline: 1.2392x; 1.2392x over previous
//
#include <hip/hip_runtime.h>
#include <stdint.h>

// Problem constants (fixed by setup_inputs)
#define B_ 64
#define C_ 256
#define H_ 56
#define W_ 56
#define HM 50              // H - (BLOCK_SIZE-1)
#define WM 50
#define NPLANES (B_ * C_)          // 16384
#define PLANE_IN (HM * WM)         // 2500
#define PLANE_OUT (H_ * W_)        // 3136
#define NTOT (NPLANES * PLANE_OUT) // 51,380,224
#define N4 (NTOT / 4)              // 12,845,056 float4s

typedef float f4 __attribute__((ext_vector_type(4)));

// One block per (b,c) plane, 4 waves. Each wave builds row bitmasks via
// __ballot (lane i supplies bit i), smears horizontally (7-wide OR), then
// 56 threads do the vertical 7-row OR, invert to keep-bits, store + count.
// NO atomics: per-block count goes to counts[blockIdx] (contention-free).
// [R1 lesson: a single-address atomicAdd from 16384 blocks serialized at
//  ~12 ns/op and cost +126 us on this kernel. Do not re-introduce it.]
__global__ __launch_bounds__(256) void dilate_kernel(
        const float* __restrict__ u,
        const float* __restrict__ gamma,
        unsigned long long* __restrict__ mask_out,   // [NPLANES * H_]
        unsigned int* __restrict__ counts) {         // [NPLANES]
    __shared__ unsigned long long hdil[HM];    // 400 B

    const int plane = blockIdx.x;
    const int tid   = threadIdx.x;
    const int wave  = tid >> 6;
    const int lane  = tid & 63;
    const float g   = gamma[0];
    const float* up = u + (size_t)plane * PLANE_IN;

    // Rows r = wave + 4*i. Lanes 0..49 load row floats (contiguous 200 B),
    // ballot packs the predicate into a 64-bit row mask in one instruction.
    #pragma unroll
    for (int i = 0; i < 13; ++i) {
        int r = wave + 4 * i;
        float v = 1e30f;                       // predicate false for idle lanes
        if (r < HM && lane < WM) v = up[r * WM + lane];
        unsigned long long bits = __ballot(v < g);
        // horizontal dilation: OR of shifts 0..6 via log-step smear
        unsigned long long h = bits | (bits << 1);
        h |= h << 2;
        h |= h << 3;
        if (lane == 0 && r < HM) hdil[r] = h;
    }
    __syncthreads();

    // Vertical dilation: output row t covers seed rows [t-6, t] ∩ [0, HM).
    unsigned int zcnt = 0;
    if (tid < H_) {
        int r0 = tid - 6; if (r0 < 0) r0 = 0;
        int r1 = tid;     if (r1 > HM - 1) r1 = HM - 1;
        unsigned long long v = 0ull;
        for (int r = r0; r <= r1; ++r) v |= hdil[r];
        unsigned long long keep = (~v) & ((1ULL << W_) - 1ULL);
        mask_out[(size_t)plane * H_ + tid] = keep;
        zcnt = (unsigned int)__popcll(keep);
    }
    // Threads 0..55 are all in wave 0: shuffle-reduce, store one count/block.
    if (tid < 64) {
        #pragma unroll
        for (int off = 32; off > 0; off >>= 1)
            zcnt += __shfl_down(zcnt, off, 64);
        if (tid == 0) counts[plane] = zcnt;
    }
}

// Single block: sum 16384 per-block counts, write final scale factor.
__global__ __launch_bounds__(256) void reduce_kernel(
        const unsigned int* __restrict__ counts,
        float* __restrict__ scale_out) {
    __shared__ unsigned int sdata[4];
    const int tid  = threadIdx.x;
    const int wave = tid >> 6;
    const int lane = tid & 63;

    unsigned int sum = 0;
    const uint4* c4 = (const uint4*)counts;            // 4096 uint4
    for (int i = tid; i < NPLANES / 4; i += 256) {
        uint4 v = c4[i];
        sum += v.x + v.y + v.z + v.w;
    }
    #pragma unroll
    for (int off = 32; off > 0; off >>= 1)
        sum += __shfl_down(sum, off, 64);
    if (lane == 0) sdata[wave] = sum;
    __syncthreads();
    if (tid == 0) {
        unsigned int total = sdata[0] + sdata[1] + sdata[2] + sdata[3];
        *scale_out = (float)NTOT / (float)total;
    }
}

// Grid-stride elementwise: out = x * scale * keep_bit.
// ~63% of pixels are dropped (gamma=0.02, 7x7 dilation -> keep = .98^49).
// Dropped runs are >=7 wide, so many full 64B cachelines of x are never
// needed — predicate the x load on (bits != 0) so masked-off lanes issue no
// memory request, cutting x FETCH roughly in half. Nontemporal hints: x and
// out are streamed exactly once; keep the 7.3 MB mask L2-resident instead.
__global__ __launch_bounds__(256) void apply_kernel(
        const float* __restrict__ x,
        const unsigned long long* __restrict__ mask,
        const float* __restrict__ scale_ptr,
        float* __restrict__ out) {
    const float scale = *scale_ptr;
    const f4* xp = (const f4*)x;
    f4*       op = (f4*)out;
    const int stride = gridDim.x * 256;

    for (int idx4 = blockIdx.x * 256 + threadIdx.x; idx4 < N4; idx4 += stride) {
        int word = idx4 / 14;            // = plane*56 + h  (W_/4 == 14)
        int w4   = idx4 - word * 14;
        unsigned int bits = (unsigned int)(mask[word] >> (w4 * 4)) & 0xFu;
        f4 o = {0.0f, 0.0f, 0.0f, 0.0f};
        if (bits) {                      // skip x fetch for fully-dropped quads
            f4 v = __builtin_nontemporal_load(&xp[idx4]);
            o.x = (bits & 1u) ? v.x * scale : 0.0f;
            o.y = (bits & 2u) ? v.y * scale : 0.0f;
            o.z = (bits & 4u) ? v.z * scale : 0.0f;
            o.w = (bits & 8u) ? v.w * scale : 0.0f;
        }
        __builtin_nontemporal_store(o, &op[idx4]);
    }
}

extern "C" void kernel_launch(void* const* d_in, const int* in_sizes, int n_in,
                              void* d_out, int out_size, void* d_ws, size_t ws_size,
                              hipStream_t stream) {
    const float* x     = (const float*)d_in[0];
    const float* u     = (const float*)d_in[1];
    const float* gamma = (const float*)d_in[2];
    float* out = (float*)d_out;

    // Workspace: [0,4) scale; [1024, 1024+64KB) per-block counts;
    //            [66560, +7.34MB) bit-packed keep mask.
    float*        scale  = (float*)d_ws;
    unsigned int* counts = (unsigned int*)((char*)d_ws + 1024);
    unsigned long long* mask =
        (unsigned long long*)((char*)d_ws + 1024 + NPLANES * sizeof(unsigned int));

    dilate_kernel<<<NPLANES, 256, 0, stream>>>(u, gamma, mask, counts);
    reduce_kernel<<<1, 256, 0, stream>>>(counts, scale);
    apply_kernel<<<4096, 256, 0, stream>>>(x, mask, scale, out);
}